// Round 3
// baseline (33751.364 us; speedup 1.0000x reference)
//
#include <hip/hip_runtime.h>
#include <hip/hip_bf16.h>

#define T_STEPS 4096
#define RES     4096
#define NIN     64
#define NOUT    32
#define NWG     256

typedef unsigned long long ull;

// ---------------------------------------------------------------------------
// Persistent recurrence kernel, plain launch (grid=256=CU count; VGPR use
// forces 1 WG/CU so all WGs are co-resident; flag-based grid barrier).
// Wave wv owns rows r0..r0+3; each thread holds 256 f32 of W in VGPRs,
// pinned there by opaque asm defs (otherwise the allocator rematerializes
// the loads into the t-loop and re-streams 64 MB of W from LLC every step —
// that was round 2's 6.5 us/step at VGPR_Count=144).
// x exchange: sc1 (agent) stores into a fresh row of the f32 history Xf[t],
// consumers use plain cached loads (fresh address each step -> no stale L2).
// ---------------------------------------------------------------------------
__global__ __launch_bounds__(256, 1)
void esn_recur(const float* __restrict__ inp,
               const float* __restrict__ Win,
               const float* __restrict__ W,
               int*   __restrict__ flags,   // [256], zeroed => "x[0] published"
               float* __restrict__ Xf)      // [T][RES] f32; row 0 pre-zeroed
{
    const int g    = blockIdx.x;
    const int tid  = threadIdx.x;
    const int wv   = tid >> 6;
    const int lane = tid & 63;
    const int r0   = g * 16 + wv * 4;

    __shared__ float xs[RES];                 // 16 KiB staged x[t-1]

    // ---- W fragment into registers (once; reused for 4095 steps) ----------
    float w[4][64];
#pragma unroll
    for (int i = 0; i < 4; ++i) {
        const float* Wr = W + (size_t)(r0 + i) * RES + 2 * lane;
#pragma unroll
        for (int c1 = 0; c1 < 32; ++c1) {
            float2 v = *(const float2*)(Wr + 128 * c1);
            w[i][2 * c1]     = v.x;
            w[i][2 * c1 + 1] = v.y;
        }
    }
    // Pin every W value in a register: an asm-defined value cannot be
    // rematerialized, so the allocator must keep it live (budget 512 VGPRs).
#pragma unroll
    for (int i = 0; i < 4; ++i)
#pragma unroll
        for (int j = 0; j < 64; ++j)
            asm("" : "+v"(w[i][j]));

    float win[4];
#pragma unroll
    for (int i = 0; i < 4; ++i)
        win[i] = Win[(size_t)(r0 + i) * NIN + lane];

    float u = inp[NIN + lane];                // u for t=1

    for (int t = 1; t < T_STEPS; ++t) {
        // ---- grid barrier: every wave polls all 256 flags ------------------
        {
            const int  want = t - 1;
            const ull* fp   = (const ull*)flags;    // 2 flags per 8B word
            for (;;) {
                ull q0 = __hip_atomic_load(fp + lane,      __ATOMIC_RELAXED, __HIP_MEMORY_SCOPE_AGENT);
                ull q1 = __hip_atomic_load(fp + 64 + lane, __ATOMIC_RELAXED, __HIP_MEMORY_SCOPE_AGENT);
                int ok = ((int)q0 >= want) & ((int)(q0 >> 32) >= want) &
                         ((int)q1 >= want) & ((int)(q1 >> 32) >= want);
                if (__all(ok)) break;
            }
        }

        // ---- stage x[t-1] into LDS (plain loads; fresh address each step) --
        const float* xrow = Xf + (size_t)(t - 1) * RES;
        asm volatile("" : "+v"(xrow));        // don't hoist loads above the spin
        {
            const float4* s4 = (const float4*)xrow;
            float4*       d4 = (float4*)xs;
#pragma unroll
            for (int k = 0; k < 4; ++k)       // 256 thr x 4 x 16B, coalesced
                d4[tid + 256 * k] = s4[tid + 256 * k];
        }

        float ucur = u;
        if (t + 1 < T_STEPS) u = inp[(size_t)(t + 1) * NIN + lane];

        __syncthreads();

        // ---- a = W_in u_t + W x_{t-1} (4 rows/wave) ------------------------
        float a0 = win[0] * ucur, a1 = win[1] * ucur,
              a2 = win[2] * ucur, a3 = win[3] * ucur;
#pragma unroll
        for (int c1 = 0; c1 < 32; ++c1) {
            float xa = xs[2 * lane + 128 * c1];
            float xb = xs[2 * lane + 128 * c1 + 1];
            a0 += w[0][2 * c1] * xa + w[0][2 * c1 + 1] * xb;
            a1 += w[1][2 * c1] * xa + w[1][2 * c1 + 1] * xb;
            a2 += w[2][2 * c1] * xa + w[2][2 * c1 + 1] * xb;
            a3 += w[3][2 * c1] * xa + w[3][2 * c1 + 1] * xb;
        }
#pragma unroll
        for (int off = 32; off > 0; off >>= 1) {
            a0 += __shfl_xor(a0, off, 64);
            a1 += __shfl_xor(a1, off, 64);
            a2 += __shfl_xor(a2, off, 64);
            a3 += __shfl_xor(a3, off, 64);
        }

        if (lane < 4) {
            float s  = (lane == 0) ? a0 : (lane == 1) ? a1 : (lane == 2) ? a2 : a3;
            float xn = tanhf(s);
            // publish row (sc1 -> LLC) so other XCDs' plain loads see it
            __hip_atomic_store(Xf + (size_t)t * RES + r0 + lane, xn,
                               __ATOMIC_RELAXED, __HIP_MEMORY_SCOPE_AGENT);
        }
        // drain this wave's sc1 stores to the coherence point before the flag
        asm volatile("s_waitcnt vmcnt(0)" ::: "memory");
        __syncthreads();
        if (tid == 0)
            __hip_atomic_store(flags + g, t, __ATOMIC_RELAXED, __HIP_MEMORY_SCOPE_AGENT);
    }
}

// ---------------------------------------------------------------------------
// Readout: out[T,32] = Xf @ W_out. 2 t-rows per block, 2048 blocks.
// ---------------------------------------------------------------------------
__global__ __launch_bounds__(256)
void esn_out(const float* __restrict__ Xf,
             const float* __restrict__ Wout,
             float* __restrict__ out)
{
    __shared__ float xs[2 * RES];             // 32 KiB
    __shared__ float red[2][8][32];
    const int tid = threadIdx.x;
    const int t0  = blockIdx.x * 2;

    const float4* s4 = (const float4*)(Xf + (size_t)t0 * RES);
    float4*       d4 = (float4*)xs;
    for (int i = tid; i < 2 * RES / 4; i += 256)
        d4[i] = s4[i];
    __syncthreads();

    const int o  = tid & 31;
    const int sg = tid >> 5;                  // 8 segments of 512
    float acc0 = 0.f, acc1 = 0.f;
    const int rbeg = sg * 512;
    for (int r = rbeg; r < rbeg + 512; ++r) {
        float wv = Wout[(size_t)r * NOUT + o];
        acc0 += xs[r] * wv;
        acc1 += xs[RES + r] * wv;
    }
    red[0][sg][o] = acc0;
    red[1][sg][o] = acc1;
    __syncthreads();

    if (tid < 64) {
        const int h = tid >> 5, oo = tid & 31;
        float s = 0.f;
#pragma unroll
        for (int k = 0; k < 8; ++k) s += red[h][k][oo];
        out[(size_t)(t0 + h) * NOUT + oo] = s;
    }
}

// ---------------------------------------------------------------------------
extern "C" void kernel_launch(void* const* d_in, const int* in_sizes, int n_in,
                              void* d_out, int out_size, void* d_ws, size_t ws_size,
                              hipStream_t stream)
{
    const float* inputs = (const float*)d_in[0];   // [T, 64]
    const float* W_in   = (const float*)d_in[1];   // [RES, 64]
    const float* W      = (const float*)d_in[2];   // [RES, RES]
    const float* W_out  = (const float*)d_in[3];   // [RES, 32]
    float* out = (float*)d_out;                    // [T, 32]

    char*  ws    = (char*)d_ws;
    int*   flags = (int*)ws;                       // 1 KiB (padded to 4 KiB)
    float* Xf    = (float*)(ws + 4096);            // 64 MiB f32 history

    // Replay-safe init (ws is NOT re-poisoned between graph replays).
    hipMemsetAsync(flags, 0, NWG * sizeof(int), stream);
    hipMemsetAsync(Xf, 0, RES * sizeof(float), stream);   // x[0] = 0

    esn_recur<<<dim3(NWG), dim3(256), 0, stream>>>(inputs, W_in, W, flags, Xf);
    esn_out<<<dim3(T_STEPS / 2), dim3(256), 0, stream>>>(Xf, W_out, out);
}

// Round 4
// 13049.890 us; speedup vs baseline: 2.5863x; 2.5863x over previous
//
#include <hip/hip_runtime.h>

#define T_STEPS 4096
#define RES     4096
#define NIN     64
#define NOUT    32
#define NWG     256
#define TPB     512   // 8 waves; 2 rows/wave; 128 W-f32 per thread

typedef unsigned long long ull;

// Published x values are encoded as x+2.0 (range (1,3)); 0.0 = not written.
__device__ __forceinline__ bool rdy(ull q) {
    return (__uint_as_float((unsigned)q) > 0.5f) &&
           (__uint_as_float((unsigned)(q >> 32)) > 0.5f);
}

__global__ void esn_init(float* __restrict__ Xf) {
    int i = blockIdx.x * 256 + threadIdx.x;
    if (i < RES) Xf[i] = 2.0f;                 // encoded x[0] = 0
}

// ---------------------------------------------------------------------------
// Persistent recurrence. 256 WGs x 512 thr. Wave wv owns rows r0, r0+1.
// Thread holds W[r0..r0+1][4*lane+256*c+k] in 128 arch VGPRs (fits < 256,
// unlike round 2/3's 256/thread which the allocator re-streamed from LLC at
// 64 MB/step — that was the whole 27-34 ms).
// Publish: sc1 store of encoded x to fresh row Xf[t] (no flags, no drain).
// Consume: each thread polls its own 32 B of Xf[t-1] with agent-scope loads,
// decodes into double-buffered LDS; one barrier per step.
// ---------------------------------------------------------------------------
__global__ __launch_bounds__(TPB, 2)
void esn_recur(const float* __restrict__ inp,
               const float* __restrict__ Win,
               const float* __restrict__ W,
               float* __restrict__ Xf)          // [T][RES], encoded
{
    const int g    = blockIdx.x;
    const int tid  = threadIdx.x;
    const int wv   = tid >> 6;
    const int lane = tid & 63;
    const int r0   = g * 16 + wv * 2;

    __shared__ float xs[2][RES];               // 32 KiB double buffer

    // ---- W fragment: 2 rows x 64 cols per thread -----------------------
    float w0[64], w1[64];
    {
        const float* Wr0 = W + (size_t)r0 * RES + 4 * lane;
        const float* Wr1 = Wr0 + RES;
#pragma unroll
        for (int c = 0; c < 16; ++c) {
            float4 a = *(const float4*)(Wr0 + 256 * c);
            float4 b = *(const float4*)(Wr1 + 256 * c);
            w0[4*c+0] = a.x; w0[4*c+1] = a.y; w0[4*c+2] = a.z; w0[4*c+3] = a.w;
            w1[4*c+0] = b.x; w1[4*c+1] = b.y; w1[4*c+2] = b.z; w1[4*c+3] = b.w;
        }
    }
    // pin in registers (fits comfortably under the 256 arch-VGPR limit now)
#pragma unroll
    for (int j = 0; j < 64; ++j) { asm("" : "+v"(w0[j])); asm("" : "+v"(w1[j])); }

    const float win0 = Win[(size_t)(r0 + 0) * NIN + lane];
    const float win1 = Win[(size_t)(r0 + 1) * NIN + lane];

    float u = inp[NIN + lane];                 // u for t=1

    for (int t = 1; t < T_STEPS; ++t) {
        // ---- poll my 32 B of x[t-1]; reload only missing chunks ---------
        const ull* src = (const ull*)(Xf + (size_t)(t - 1) * RES) + tid * 4;
        ull q0 = 0, q1 = 0, q2 = 0, q3 = 0;
        int need = 15;
        do {
            if (need & 1) { q0 = __hip_atomic_load(src + 0, __ATOMIC_RELAXED, __HIP_MEMORY_SCOPE_AGENT); if (rdy(q0)) need &= ~1; }
            if (need & 2) { q1 = __hip_atomic_load(src + 1, __ATOMIC_RELAXED, __HIP_MEMORY_SCOPE_AGENT); if (rdy(q1)) need &= ~2; }
            if (need & 4) { q2 = __hip_atomic_load(src + 2, __ATOMIC_RELAXED, __HIP_MEMORY_SCOPE_AGENT); if (rdy(q2)) need &= ~4; }
            if (need & 8) { q3 = __hip_atomic_load(src + 3, __ATOMIC_RELAXED, __HIP_MEMORY_SCOPE_AGENT); if (rdy(q3)) need &= ~8; }
        } while (need);

        float* dst = &xs[t & 1][tid * 8];
        ((float4*)dst)[0] = make_float4(
            __uint_as_float((unsigned)q0)         - 2.0f,
            __uint_as_float((unsigned)(q0 >> 32)) - 2.0f,
            __uint_as_float((unsigned)q1)         - 2.0f,
            __uint_as_float((unsigned)(q1 >> 32)) - 2.0f);
        ((float4*)dst)[1] = make_float4(
            __uint_as_float((unsigned)q2)         - 2.0f,
            __uint_as_float((unsigned)(q2 >> 32)) - 2.0f,
            __uint_as_float((unsigned)q3)         - 2.0f,
            __uint_as_float((unsigned)(q3 >> 32)) - 2.0f);

        float ucur = u;
        if (t + 1 < T_STEPS) u = inp[(size_t)(t + 1) * NIN + lane];

        __syncthreads();                       // buffer (t&1) fully staged

        // ---- a = W_in u_t + W x_{t-1} (2 rows/wave) ---------------------
        float a0 = win0 * ucur, a1 = win1 * ucur;
        const float4* xv = (const float4*)&xs[t & 1][4 * lane];
#pragma unroll
        for (int c = 0; c < 16; ++c) {
            float4 x4 = xv[64 * c];
            a0 += w0[4*c+0]*x4.x + w0[4*c+1]*x4.y + w0[4*c+2]*x4.z + w0[4*c+3]*x4.w;
            a1 += w1[4*c+0]*x4.x + w1[4*c+1]*x4.y + w1[4*c+2]*x4.z + w1[4*c+3]*x4.w;
        }
#pragma unroll
        for (int off = 32; off > 0; off >>= 1) {
            a0 += __shfl_xor(a0, off, 64);
            a1 += __shfl_xor(a1, off, 64);
        }

        if (lane < 2) {
            float s  = lane ? a1 : a0;
            float xn = tanhf(s);
            // fire-and-forget publish; the value itself is the ready flag
            __hip_atomic_store(Xf + (size_t)t * RES + r0 + lane, xn + 2.0f,
                               __ATOMIC_RELAXED, __HIP_MEMORY_SCOPE_AGENT);
        }
        // next iteration writes the other LDS buffer; the single barrier
        // above guarantees no wave can overwrite a buffer still being read.
    }
}

// ---------------------------------------------------------------------------
// Readout: out[T,32] = decode(Xf) @ W_out. 2 t-rows/block.
// ---------------------------------------------------------------------------
__global__ __launch_bounds__(256)
void esn_out(const float* __restrict__ Xf,
             const float* __restrict__ Wout,
             float* __restrict__ out)
{
    __shared__ float xs[2 * RES];
    __shared__ float red[2][8][32];
    const int tid = threadIdx.x;
    const int t0  = blockIdx.x * 2;

    const float4* s4 = (const float4*)(Xf + (size_t)t0 * RES);
    float4*       d4 = (float4*)xs;
    for (int i = tid; i < 2 * RES / 4; i += 256) {
        float4 v = s4[i];
        v.x -= 2.0f; v.y -= 2.0f; v.z -= 2.0f; v.w -= 2.0f;   // decode
        d4[i] = v;
    }
    __syncthreads();

    const int o  = tid & 31;
    const int sg = tid >> 5;
    float acc0 = 0.f, acc1 = 0.f;
    const int rbeg = sg * 512;
    for (int r = rbeg; r < rbeg + 512; ++r) {
        float wv = Wout[(size_t)r * NOUT + o];
        acc0 += xs[r] * wv;
        acc1 += xs[RES + r] * wv;
    }
    red[0][sg][o] = acc0;
    red[1][sg][o] = acc1;
    __syncthreads();

    if (tid < 64) {
        const int h = tid >> 5, oo = tid & 31;
        float s = 0.f;
#pragma unroll
        for (int k = 0; k < 8; ++k) s += red[h][k][oo];
        out[(size_t)(t0 + h) * NOUT + oo] = s;
    }
}

// ---------------------------------------------------------------------------
extern "C" void kernel_launch(void* const* d_in, const int* in_sizes, int n_in,
                              void* d_out, int out_size, void* d_ws, size_t ws_size,
                              hipStream_t stream)
{
    const float* inputs = (const float*)d_in[0];   // [T, 64]
    const float* W_in   = (const float*)d_in[1];   // [RES, 64]
    const float* W      = (const float*)d_in[2];   // [RES, RES]
    const float* W_out  = (const float*)d_in[3];   // [RES, 32]
    float* out = (float*)d_out;                    // [T, 32]

    float* Xf = (float*)d_ws;                      // [T][RES] encoded, 64 MiB

    // Replay-safe: zero the whole history (0.0 = "not written"), re-encode
    // row 0. Graph-capturable (async memset + kernels only).
    hipMemsetAsync(Xf, 0, (size_t)T_STEPS * RES * sizeof(float), stream);
    esn_init<<<dim3((RES + 255) / 256), dim3(256), 0, stream>>>(Xf);

    esn_recur<<<dim3(NWG), dim3(TPB), 0, stream>>>(inputs, W_in, W, Xf);
    esn_out<<<dim3(T_STEPS / 2), dim3(256), 0, stream>>>(Xf, W_out, out);
}

// Round 5
// 13041.113 us; speedup vs baseline: 2.5881x; 1.0007x over previous
//
#include <hip/hip_runtime.h>

#define T_STEPS 4096
#define RES     4096
#define NIN     64
#define NOUT    32
#define NWG     256
#define TPB     512   // 8 waves; 2 rows/wave; 128 W-f32 per thread

typedef unsigned long long ull;

// Published x values are encoded as x+2.0 (range (1,3)); 0.0 = not written.
__device__ __forceinline__ bool rdy(ull q) {
    return (__uint_as_float((unsigned)q) > 0.5f) &&
           (__uint_as_float((unsigned)(q >> 32)) > 0.5f);
}

__global__ void esn_init(float* __restrict__ Xf) {
    int i = blockIdx.x * 256 + threadIdx.x;
    if (i < RES) Xf[i] = 2.0f;                 // encoded x[0] = 0
}

// ---------------------------------------------------------------------------
// Persistent recurrence. 256 WGs x 512 thr. Wave wv owns rows r0, r0+1.
// Thread holds W[r0..r0+1][4*lane+256*c+k] in 128 arch VGPRs.
// KEY (rounds 2-4 post-mortem): the pin must be `asm volatile`. A non-volatile
// asm is side-effect-free and gets SUNK to its uses inside the t-loop, which
// re-legalizes rematerialization of the W loads -> 64 MB/step re-streamed
// from L2/LLC (that was the entire 13-34 ms). Volatile asm cannot be sunk,
// so the 128 results stay live for all 4095 steps; budget is 256 VGPRs
// (__launch_bounds__(512,2) -> 8 waves/CU).
// Publish: sc1 store of encoded x to fresh row Xf[t] (no flags, no drain).
// Consume: each thread polls its own 32 B of Xf[t-1] with agent-scope loads,
// decodes into double-buffered LDS; one barrier per step.
// ---------------------------------------------------------------------------
__global__ __launch_bounds__(TPB, 2)
void esn_recur(const float* __restrict__ inp,
               const float* __restrict__ Win,
               const float* __restrict__ W,
               float* __restrict__ Xf)          // [T][RES], encoded
{
    const int g    = blockIdx.x;
    const int tid  = threadIdx.x;
    const int wv   = tid >> 6;
    const int lane = tid & 63;
    const int r0   = g * 16 + wv * 2;

    __shared__ float xs[2][RES];               // 32 KiB double buffer

    // ---- W fragment: 2 rows x 64 cols per thread -----------------------
    float w0[64], w1[64];
    {
        const float* Wr0 = W + (size_t)r0 * RES + 4 * lane;
        const float* Wr1 = Wr0 + RES;
#pragma unroll
        for (int c = 0; c < 16; ++c) {
            float4 a = *(const float4*)(Wr0 + 256 * c);
            float4 b = *(const float4*)(Wr1 + 256 * c);
            w0[4*c+0] = a.x; w0[4*c+1] = a.y; w0[4*c+2] = a.z; w0[4*c+3] = a.w;
            w1[4*c+0] = b.x; w1[4*c+1] = b.y; w1[4*c+2] = b.z; w1[4*c+3] = b.w;
        }
    }
    // VOLATILE pin: cannot be sunk/duplicated -> values stay in VGPRs for the
    // whole kernel instead of being re-loaded every step.
#pragma unroll
    for (int j = 0; j < 64; ++j) {
        asm volatile("" : "+v"(w0[j]));
        asm volatile("" : "+v"(w1[j]));
    }

    const float win0 = Win[(size_t)(r0 + 0) * NIN + lane];
    const float win1 = Win[(size_t)(r0 + 1) * NIN + lane];

    float u = inp[NIN + lane];                 // u for t=1

    for (int t = 1; t < T_STEPS; ++t) {
        // ---- poll my 32 B of x[t-1]; reload only missing chunks ---------
        const ull* src = (const ull*)(Xf + (size_t)(t - 1) * RES) + tid * 4;
        ull q0 = 0, q1 = 0, q2 = 0, q3 = 0;
        int need = 15;
        do {
            if (need & 1) { q0 = __hip_atomic_load(src + 0, __ATOMIC_RELAXED, __HIP_MEMORY_SCOPE_AGENT); if (rdy(q0)) need &= ~1; }
            if (need & 2) { q1 = __hip_atomic_load(src + 1, __ATOMIC_RELAXED, __HIP_MEMORY_SCOPE_AGENT); if (rdy(q1)) need &= ~2; }
            if (need & 4) { q2 = __hip_atomic_load(src + 2, __ATOMIC_RELAXED, __HIP_MEMORY_SCOPE_AGENT); if (rdy(q2)) need &= ~4; }
            if (need & 8) { q3 = __hip_atomic_load(src + 3, __ATOMIC_RELAXED, __HIP_MEMORY_SCOPE_AGENT); if (rdy(q3)) need &= ~8; }
        } while (need);

        float* dst = &xs[t & 1][tid * 8];
        ((float4*)dst)[0] = make_float4(
            __uint_as_float((unsigned)q0)         - 2.0f,
            __uint_as_float((unsigned)(q0 >> 32)) - 2.0f,
            __uint_as_float((unsigned)q1)         - 2.0f,
            __uint_as_float((unsigned)(q1 >> 32)) - 2.0f);
        ((float4*)dst)[1] = make_float4(
            __uint_as_float((unsigned)q2)         - 2.0f,
            __uint_as_float((unsigned)(q2 >> 32)) - 2.0f,
            __uint_as_float((unsigned)q3)         - 2.0f,
            __uint_as_float((unsigned)(q3 >> 32)) - 2.0f);

        float ucur = u;
        if (t + 1 < T_STEPS) u = inp[(size_t)(t + 1) * NIN + lane];

        __syncthreads();                       // buffer (t&1) fully staged

        // ---- a = W_in u_t + W x_{t-1} (2 rows/wave) ---------------------
        float a0 = win0 * ucur, a1 = win1 * ucur;
        const float4* xv = (const float4*)&xs[t & 1][4 * lane];
#pragma unroll
        for (int c = 0; c < 16; ++c) {
            float4 x4 = xv[64 * c];
            a0 += w0[4*c+0]*x4.x + w0[4*c+1]*x4.y + w0[4*c+2]*x4.z + w0[4*c+3]*x4.w;
            a1 += w1[4*c+0]*x4.x + w1[4*c+1]*x4.y + w1[4*c+2]*x4.z + w1[4*c+3]*x4.w;
        }
#pragma unroll
        for (int off = 32; off > 0; off >>= 1) {
            a0 += __shfl_xor(a0, off, 64);
            a1 += __shfl_xor(a1, off, 64);
        }

        if (lane < 2) {
            float s  = lane ? a1 : a0;
            float xn = tanhf(s);
            // fire-and-forget publish; the value itself is the ready flag
            __hip_atomic_store(Xf + (size_t)t * RES + r0 + lane, xn + 2.0f,
                               __ATOMIC_RELAXED, __HIP_MEMORY_SCOPE_AGENT);
        }
        // next iteration writes the other LDS buffer; the single barrier
        // above guarantees no wave can overwrite a buffer still being read.
    }
}

// ---------------------------------------------------------------------------
// Readout: out[T,32] = decode(Xf) @ W_out. 2 t-rows/block.
// ---------------------------------------------------------------------------
__global__ __launch_bounds__(256)
void esn_out(const float* __restrict__ Xf,
             const float* __restrict__ Wout,
             float* __restrict__ out)
{
    __shared__ float xs[2 * RES];
    __shared__ float red[2][8][32];
    const int tid = threadIdx.x;
    const int t0  = blockIdx.x * 2;

    const float4* s4 = (const float4*)(Xf + (size_t)t0 * RES);
    float4*       d4 = (float4*)xs;
    for (int i = tid; i < 2 * RES / 4; i += 256) {
        float4 v = s4[i];
        v.x -= 2.0f; v.y -= 2.0f; v.z -= 2.0f; v.w -= 2.0f;   // decode
        d4[i] = v;
    }
    __syncthreads();

    const int o  = tid & 31;
    const int sg = tid >> 5;
    float acc0 = 0.f, acc1 = 0.f;
    const int rbeg = sg * 512;
    for (int r = rbeg; r < rbeg + 512; ++r) {
        float wv = Wout[(size_t)r * NOUT + o];
        acc0 += xs[r] * wv;
        acc1 += xs[RES + r] * wv;
    }
    red[0][sg][o] = acc0;
    red[1][sg][o] = acc1;
    __syncthreads();

    if (tid < 64) {
        const int h = tid >> 5, oo = tid & 31;
        float s = 0.f;
#pragma unroll
        for (int k = 0; k < 8; ++k) s += red[h][k][oo];
        out[(size_t)(t0 + h) * NOUT + oo] = s;
    }
}

// ---------------------------------------------------------------------------
extern "C" void kernel_launch(void* const* d_in, const int* in_sizes, int n_in,
                              void* d_out, int out_size, void* d_ws, size_t ws_size,
                              hipStream_t stream)
{
    const float* inputs = (const float*)d_in[0];   // [T, 64]
    const float* W_in   = (const float*)d_in[1];   // [RES, 64]
    const float* W      = (const float*)d_in[2];   // [RES, RES]
    const float* W_out  = (const float*)d_in[3];   // [RES, 32]
    float* out = (float*)d_out;                    // [T, 32]

    float* Xf = (float*)d_ws;                      // [T][RES] encoded, 64 MiB

    // Replay-safe: zero the whole history (0.0 = "not written"), re-encode
    // row 0. Graph-capturable (async memset + kernels only).
    hipMemsetAsync(Xf, 0, (size_t)T_STEPS * RES * sizeof(float), stream);
    esn_init<<<dim3((RES + 255) / 256), dim3(256), 0, stream>>>(Xf);

    esn_recur<<<dim3(NWG), dim3(TPB), 0, stream>>>(inputs, W_in, W, Xf);
    esn_out<<<dim3(T_STEPS / 2), dim3(256), 0, stream>>>(Xf, W_out, out);
}